// Round 2
// baseline (1095.849 us; speedup 1.0000x reference)
//
#include <hip/hip_runtime.h>
#include <math.h>

// Problem constants
#define F_DIM 256
#define N_DIM 400
#define C_DIM 128
#define H_DIM 8
#define E_DIM 16
#define ROWS  (F_DIM * N_DIM)          // 102400
#define SBUF  (N_DIM * H_DIM * F_DIM * E_DIM)  // 13107200 floats per q/k/v buffer

// ---------------------------------------------------------------------------
// K0: tree_k = tree_encoding @ W_tree_k ; tree_v = tree_encoding @ W_tree_v
// grid 400, block 256 (first 128 threads -> tk, last 128 -> tv)
// ---------------------------------------------------------------------------
__global__ __launch_bounds__(256) void tree_proj(
    const float* __restrict__ te, const float* __restrict__ Wtk,
    const float* __restrict__ Wtv, float* __restrict__ tk, float* __restrict__ tv)
{
    int n = blockIdx.x;
    int t = threadIdx.x;
    const float* W = (t < 128) ? Wtk : Wtv;
    float* outp    = (t < 128) ? tk : tv;
    int j = t & 127;
    float acc = 0.f;
    #pragma unroll 4
    for (int c = 0; c < 128; ++c)
        acc += te[n * 128 + c] * W[c * 128 + j];
    outp[n * 128 + j] = acc;
}

// ---------------------------------------------------------------------------
// K1: qkv = x @ W_qkv^T, scatter q/k/v into (n,h,f,e) layout, add tree terms.
// Tiled GEMM: BM=64, BN=64, BK=16, 256 threads, 4x4 microtile.
// grid (384/64=6, 102400/64=1600)
// ---------------------------------------------------------------------------
__global__ __launch_bounds__(256) void qkv_gemm(
    const float* __restrict__ x, const float* __restrict__ Wq,
    const float* __restrict__ tk, const float* __restrict__ tv,
    float* __restrict__ qb, float* __restrict__ kb, float* __restrict__ vb)
{
    __shared__ float As[16 * 68];
    __shared__ float Bs[16 * 68];
    int tid = threadIdx.x;
    int bx = blockIdx.x, by = blockIdx.y;
    int ty = tid >> 4, tx = tid & 15;
    float acc[4][4] = {};

    int a_r = tid >> 2;          // 0..63
    int a_k = (tid & 3) * 4;     // 0,4,8,12

    for (int k0 = 0; k0 < 128; k0 += 16) {
        float4 av = *(const float4*)(x  + (by * 64 + a_r) * 128 + k0 + a_k);
        float4 bv = *(const float4*)(Wq + (bx * 64 + a_r) * 128 + k0 + a_k);
        As[(a_k + 0) * 68 + a_r] = av.x;
        As[(a_k + 1) * 68 + a_r] = av.y;
        As[(a_k + 2) * 68 + a_r] = av.z;
        As[(a_k + 3) * 68 + a_r] = av.w;
        Bs[(a_k + 0) * 68 + a_r] = bv.x;
        Bs[(a_k + 1) * 68 + a_r] = bv.y;
        Bs[(a_k + 2) * 68 + a_r] = bv.z;
        Bs[(a_k + 3) * 68 + a_r] = bv.w;
        __syncthreads();
        #pragma unroll
        for (int k = 0; k < 16; ++k) {
            float4 a4 = *(const float4*)(As + k * 68 + ty * 4);
            float4 b4 = *(const float4*)(Bs + k * 68 + tx * 4);
            acc[0][0] += a4.x * b4.x; acc[0][1] += a4.x * b4.y;
            acc[0][2] += a4.x * b4.z; acc[0][3] += a4.x * b4.w;
            acc[1][0] += a4.y * b4.x; acc[1][1] += a4.y * b4.y;
            acc[1][2] += a4.y * b4.z; acc[1][3] += a4.y * b4.w;
            acc[2][0] += a4.z * b4.x; acc[2][1] += a4.z * b4.y;
            acc[2][2] += a4.z * b4.z; acc[2][3] += a4.z * b4.w;
            acc[3][0] += a4.w * b4.x; acc[3][1] += a4.w * b4.y;
            acc[3][2] += a4.w * b4.z; acc[3][3] += a4.w * b4.w;
        }
        __syncthreads();
    }

    // epilogue: scatter to (n,h,f,e); sec is uniform per block (bx*64 multiple of 64)
    #pragma unroll
    for (int i = 0; i < 4; ++i) {
        int r = by * 64 + ty * 4 + i;   // r = f*400 + n
        int f = r / 400;
        int n = r - f * 400;
        #pragma unroll
        for (int j = 0; j < 4; ++j) {
            int o   = bx * 64 + tx * 4 + j;
            int sec = o >> 7;
            int rem = o & 127;
            int h = rem >> 4, e = rem & 15;
            int dst = ((n * 8 + h) * 256 + f) * 16 + e;
            float val = acc[i][j];
            if (sec == 0)       qb[dst] = val;
            else if (sec == 1)  kb[dst] = val + tk[n * 128 + rem];
            else                vb[dst] = val + tv[n * 128 + rem];
        }
    }
}

// ---------------------------------------------------------------------------
// K2: fused attention per (n,h). Thread t owns query row l=t.
// S[l,s] = Q[l].K[s] + (Q[l]+K[s]).emb[clip(l-s)+128]; softmax over s; out@V.
// LDS: K 16KB, V 16KB, emb (257 x stride-17) 17.5KB.  grid 3200, block 256.
// ---------------------------------------------------------------------------
__global__ __launch_bounds__(256) void attn_kernel(
    const float* __restrict__ qb, const float* __restrict__ kb,
    const float* __restrict__ vb, const float* __restrict__ emb,
    float* __restrict__ y)
{
    __shared__ float Ks[4096];
    __shared__ float Vs[4096];
    __shared__ float Es[257 * 17];

    int tid = threadIdx.x;
    int bn  = blockIdx.x;           // bn = n*8 + h
    int n   = bn >> 3, h = bn & 7;
    int base = bn * 4096;

    float4*       K4 = (float4*)Ks;
    float4*       V4 = (float4*)Vs;
    const float4* kg = (const float4*)(kb + base);
    const float4* vg = (const float4*)(vb + base);
    #pragma unroll
    for (int i = 0; i < 4; ++i) {
        K4[tid + i * 256] = kg[tid + i * 256];
        V4[tid + i * 256] = vg[tid + i * 256];
    }
    for (int idx = tid; idx < 257 * 16; idx += 256)
        Es[(idx >> 4) * 17 + (idx & 15)] = emb[idx];

    float q[16];
    {
        const float4* qg = (const float4*)(qb + base + tid * 16);
        float4 q0 = qg[0], q1 = qg[1], q2 = qg[2], q3 = qg[3];
        q[0]=q0.x; q[1]=q0.y; q[2]=q0.z; q[3]=q0.w;
        q[4]=q1.x; q[5]=q1.y; q[6]=q1.z; q[7]=q1.w;
        q[8]=q2.x; q[9]=q2.y; q[10]=q2.z; q[11]=q2.w;
        q[12]=q3.x; q[13]=q3.y; q[14]=q3.z; q[15]=q3.w;
    }
    __syncthreads();

    float o[16];
    #pragma unroll
    for (int i = 0; i < 16; ++i) o[i] = 0.f;
    float denom = 0.f;
    int l = tid;
    const float4* K4c = (const float4*)Ks;
    const float4* V4c = (const float4*)Vs;

    for (int s = 0; s < 256; ++s) {
        int d = l - s;
        d = (d < -128) ? -128 : ((d > 128) ? 128 : d);
        d += 128;
        const float* er = Es + d * 17;
        float s1 = 0.f, s2 = 0.f;
        #pragma unroll
        for (int g = 0; g < 4; ++g) {
            float4 kv = K4c[s * 4 + g];
            float e0 = er[g * 4 + 0], e1 = er[g * 4 + 1];
            float e2 = er[g * 4 + 2], e3 = er[g * 4 + 3];
            float q0 = q[g * 4 + 0], q1 = q[g * 4 + 1];
            float q2 = q[g * 4 + 2], q3 = q[g * 4 + 3];
            s1 += q0 * kv.x + q1 * kv.y + q2 * kv.z + q3 * kv.w;
            s2 += (q0 + kv.x) * e0 + (q1 + kv.y) * e1
                + (q2 + kv.z) * e2 + (q3 + kv.w) * e3;
        }
        // softmax without max-subtraction: logits are small (|x|<~3), exp safe
        float p = __expf((s1 + s2) * 0.25f);
        denom += p;
        #pragma unroll
        for (int g = 0; g < 4; ++g) {
            float4 vv = V4c[s * 4 + g];
            o[g * 4 + 0] += p * vv.x;
            o[g * 4 + 1] += p * vv.y;
            o[g * 4 + 2] += p * vv.z;
            o[g * 4 + 3] += p * vv.w;
        }
    }

    float inv = 1.0f / denom;
    float* yo = y + (l * 400 + n) * 128 + h * 16;
    float4* yo4 = (float4*)yo;
    yo4[0] = make_float4(o[0]*inv,  o[1]*inv,  o[2]*inv,  o[3]*inv);
    yo4[1] = make_float4(o[4]*inv,  o[5]*inv,  o[6]*inv,  o[7]*inv);
    yo4[2] = make_float4(o[8]*inv,  o[9]*inv,  o[10]*inv, o[11]*inv);
    yo4[3] = make_float4(o[12]*inv, o[13]*inv, o[14]*inv, o[15]*inv);
}

// ---------------------------------------------------------------------------
// K3: gate = sigmoid([y,x,y-x]@W_beta^T); z = g*x+(1-g)*y; h1 = LN1(z)
// grid 102400, block 128 (one row per block)
// ---------------------------------------------------------------------------
__global__ __launch_bounds__(128) void gate_ln1(
    const float* __restrict__ x, const float* __restrict__ y,
    const float* __restrict__ Wb, const float* __restrict__ g,
    const float* __restrict__ b, float* __restrict__ h1)
{
    __shared__ float sred[4];
    int r = blockIdx.x, c = threadIdx.x;
    float xv = x[r * 128 + c];
    float yv = y[r * 128 + c];
    float sv = yv * Wb[c] + xv * Wb[128 + c] + (yv - xv) * Wb[256 + c];
    int wid = c >> 6, lane = c & 63;
    #pragma unroll
    for (int off = 32; off > 0; off >>= 1) sv += __shfl_down(sv, off);
    if (lane == 0) sred[wid] = sv;
    __syncthreads();
    float total = sred[0] + sred[1];
    float gate = 1.0f / (1.0f + __expf(-total));
    float z = gate * xv + (1.0f - gate) * yv;

    float z1 = z, z2 = z * z;
    #pragma unroll
    for (int off = 32; off > 0; off >>= 1) {
        z1 += __shfl_down(z1, off);
        z2 += __shfl_down(z2, off);
    }
    __syncthreads();   // protect sred reuse
    if (lane == 0) { sred[wid] = z1; sred[2 + wid] = z2; }
    __syncthreads();
    float S1 = sred[0] + sred[1];
    float S2 = sred[2] + sred[3];
    float mu  = S1 * (1.0f / 128.0f);
    float var = S2 * (1.0f / 128.0f) - mu * mu;
    float rs  = rsqrtf(var + 1e-5f);
    h1[r * 128 + c] = (z - mu) * rs * g[c] + b[c];
}

// ---------------------------------------------------------------------------
// K4: ff1 = gelu_exact(h1 @ W1^T + b1).  Same tiling as K1, N=128.
// grid (2, 1600)
// ---------------------------------------------------------------------------
__global__ __launch_bounds__(256) void ff1_gemm(
    const float* __restrict__ A, const float* __restrict__ W,
    const float* __restrict__ bias, float* __restrict__ outp)
{
    __shared__ float As[16 * 68];
    __shared__ float Bs[16 * 68];
    int tid = threadIdx.x;
    int bx = blockIdx.x, by = blockIdx.y;
    int ty = tid >> 4, tx = tid & 15;
    float acc[4][4] = {};
    int a_r = tid >> 2;
    int a_k = (tid & 3) * 4;

    for (int k0 = 0; k0 < 128; k0 += 16) {
        float4 av = *(const float4*)(A + (by * 64 + a_r) * 128 + k0 + a_k);
        float4 bv = *(const float4*)(W + (bx * 64 + a_r) * 128 + k0 + a_k);
        As[(a_k + 0) * 68 + a_r] = av.x;
        As[(a_k + 1) * 68 + a_r] = av.y;
        As[(a_k + 2) * 68 + a_r] = av.z;
        As[(a_k + 3) * 68 + a_r] = av.w;
        Bs[(a_k + 0) * 68 + a_r] = bv.x;
        Bs[(a_k + 1) * 68 + a_r] = bv.y;
        Bs[(a_k + 2) * 68 + a_r] = bv.z;
        Bs[(a_k + 3) * 68 + a_r] = bv.w;
        __syncthreads();
        #pragma unroll
        for (int k = 0; k < 16; ++k) {
            float4 a4 = *(const float4*)(As + k * 68 + ty * 4);
            float4 b4 = *(const float4*)(Bs + k * 68 + tx * 4);
            acc[0][0] += a4.x * b4.x; acc[0][1] += a4.x * b4.y;
            acc[0][2] += a4.x * b4.z; acc[0][3] += a4.x * b4.w;
            acc[1][0] += a4.y * b4.x; acc[1][1] += a4.y * b4.y;
            acc[1][2] += a4.y * b4.z; acc[1][3] += a4.y * b4.w;
            acc[2][0] += a4.z * b4.x; acc[2][1] += a4.z * b4.y;
            acc[2][2] += a4.z * b4.z; acc[2][3] += a4.z * b4.w;
            acc[3][0] += a4.w * b4.x; acc[3][1] += a4.w * b4.y;
            acc[3][2] += a4.w * b4.z; acc[3][3] += a4.w * b4.w;
        }
        __syncthreads();
    }
    #pragma unroll
    for (int i = 0; i < 4; ++i) {
        int r = by * 64 + ty * 4 + i;
        #pragma unroll
        for (int j = 0; j < 4; ++j) {
            int o = bx * 64 + tx * 4 + j;
            float v = acc[i][j] + bias[o];
            v = 0.5f * v * (1.0f + erff(v * 0.70710678118654752f));  // exact GELU
            outp[r * 128 + o] = v;
        }
    }
}

// ---------------------------------------------------------------------------
// K5: out = LN2(ff1 @ W2^T + b2 + h1).  BM=32, BN=128 (full row), BK=16.
// 256 threads: ty=tid>>5 (8 row groups of 4), tx=tid&31 (32 col groups of 4).
// LN reduction via shfl_xor within 32-lane groups.  grid 3200.
// ---------------------------------------------------------------------------
__global__ __launch_bounds__(256) void ff2_ln2(
    const float* __restrict__ A, const float* __restrict__ W2,
    const float* __restrict__ b2, const float* __restrict__ h1,
    const float* __restrict__ g, const float* __restrict__ bb,
    float* __restrict__ outp)
{
    __shared__ float As[16 * 36];
    __shared__ float Bs[16 * 132];
    int tid = threadIdx.x;
    int by = blockIdx.x;
    int ty = tid >> 5, tx = tid & 31;
    float acc[4][4] = {};

    for (int k0 = 0; k0 < 128; k0 += 16) {
        if (tid < 128) {
            int a_r = tid >> 2;          // 0..31
            int a_k = (tid & 3) * 4;
            float4 av = *(const float4*)(A + (by * 32 + a_r) * 128 + k0 + a_k);
            As[(a_k + 0) * 36 + a_r] = av.x;
            As[(a_k + 1) * 36 + a_r] = av.y;
            As[(a_k + 2) * 36 + a_r] = av.z;
            As[(a_k + 3) * 36 + a_r] = av.w;
        }
        {
            int b_j = tid >> 1;          // 0..127
            int b_k = (tid & 1) * 8;
            float4 b0 = *(const float4*)(W2 + b_j * 128 + k0 + b_k);
            float4 b1 = *(const float4*)(W2 + b_j * 128 + k0 + b_k + 4);
            Bs[(b_k + 0) * 132 + b_j] = b0.x;
            Bs[(b_k + 1) * 132 + b_j] = b0.y;
            Bs[(b_k + 2) * 132 + b_j] = b0.z;
            Bs[(b_k + 3) * 132 + b_j] = b0.w;
            Bs[(b_k + 4) * 132 + b_j] = b1.x;
            Bs[(b_k + 5) * 132 + b_j] = b1.y;
            Bs[(b_k + 6) * 132 + b_j] = b1.z;
            Bs[(b_k + 7) * 132 + b_j] = b1.w;
        }
        __syncthreads();
        #pragma unroll
        for (int k = 0; k < 16; ++k) {
            float4 a4 = *(const float4*)(As + k * 36 + ty * 4);
            float4 b4 = *(const float4*)(Bs + k * 132 + tx * 4);
            acc[0][0] += a4.x * b4.x; acc[0][1] += a4.x * b4.y;
            acc[0][2] += a4.x * b4.z; acc[0][3] += a4.x * b4.w;
            acc[1][0] += a4.y * b4.x; acc[1][1] += a4.y * b4.y;
            acc[1][2] += a4.y * b4.z; acc[1][3] += a4.y * b4.w;
            acc[2][0] += a4.z * b4.x; acc[2][1] += a4.z * b4.y;
            acc[2][2] += a4.z * b4.z; acc[2][3] += a4.z * b4.w;
            acc[3][0] += a4.w * b4.x; acc[3][1] += a4.w * b4.y;
            acc[3][2] += a4.w * b4.z; acc[3][3] += a4.w * b4.w;
        }
        __syncthreads();
    }

    float4 bias4 = *(const float4*)(b2 + tx * 4);
    float4 g4    = *(const float4*)(g  + tx * 4);
    float4 bb4   = *(const float4*)(bb + tx * 4);
    float z[4][4];
    float s1[4], s2[4];
    #pragma unroll
    for (int i = 0; i < 4; ++i) {
        int r = by * 32 + ty * 4 + i;
        float4 hv = *(const float4*)(h1 + r * 128 + tx * 4);
        z[i][0] = acc[i][0] + bias4.x + hv.x;
        z[i][1] = acc[i][1] + bias4.y + hv.y;
        z[i][2] = acc[i][2] + bias4.z + hv.z;
        z[i][3] = acc[i][3] + bias4.w + hv.w;
        s1[i] = z[i][0] + z[i][1] + z[i][2] + z[i][3];
        s2[i] = z[i][0]*z[i][0] + z[i][1]*z[i][1] + z[i][2]*z[i][2] + z[i][3]*z[i][3];
    }
    #pragma unroll
    for (int off = 16; off > 0; off >>= 1) {
        #pragma unroll
        for (int i = 0; i < 4; ++i) {
            s1[i] += __shfl_xor(s1[i], off);
            s2[i] += __shfl_xor(s2[i], off);
        }
    }
    #pragma unroll
    for (int i = 0; i < 4; ++i) {
        int r = by * 32 + ty * 4 + i;
        float mu  = s1[i] * (1.0f / 128.0f);
        float var = s2[i] * (1.0f / 128.0f) - mu * mu;
        float rs  = rsqrtf(var + 1e-5f);
        float4 ov;
        ov.x = (z[i][0] - mu) * rs * g4.x + bb4.x;
        ov.y = (z[i][1] - mu) * rs * g4.y + bb4.y;
        ov.z = (z[i][2] - mu) * rs * g4.z + bb4.z;
        ov.w = (z[i][3] - mu) * rs * g4.w + bb4.w;
        *(float4*)(outp + r * 128 + tx * 4) = ov;
    }
}

// ---------------------------------------------------------------------------
extern "C" void kernel_launch(void* const* d_in, const int* in_sizes, int n_in,
                              void* d_out, int out_size, void* d_ws, size_t ws_size,
                              hipStream_t stream)
{
    const float* x     = (const float*)d_in[0];
    const float* te    = (const float*)d_in[1];
    const float* Wqkv  = (const float*)d_in[2];
    const float* Wtk   = (const float*)d_in[3];
    const float* Wtv   = (const float*)d_in[4];
    const float* emb   = (const float*)d_in[5];
    const float* Wbeta = (const float*)d_in[6];
    const float* ln1g  = (const float*)d_in[7];
    const float* ln1b  = (const float*)d_in[8];
    const float* ln2g  = (const float*)d_in[9];
    const float* ln2b  = (const float*)d_in[10];
    const float* W1    = (const float*)d_in[11];
    const float* b1    = (const float*)d_in[12];
    const float* W2    = (const float*)d_in[13];
    const float* b2    = (const float*)d_in[14];
    float* outp = (float*)d_out;

    float* ws = (float*)d_ws;
    float* tk = ws;                       // 51200
    float* tv = ws + 51200;               // 51200
    float* qb = ws + 102400;              // SBUF
    float* kb = qb + SBUF;                // SBUF
    float* vb = kb + SBUF;                // SBUF
    float* yb = vb + SBUF;                // SBUF  (f,n,c)
    float* h1 = kb;                       // reuse: k dead after attention
    float* ff1 = qb;                      // reuse: q dead after attention

    tree_proj<<<400, 256, 0, stream>>>(te, Wtk, Wtv, tk, tv);
    qkv_gemm<<<dim3(6, 1600), 256, 0, stream>>>(x, Wqkv, tk, tv, qb, kb, vb);
    attn_kernel<<<3200, 256, 0, stream>>>(qb, kb, vb, emb, yb);
    gate_ln1<<<ROWS, 128, 0, stream>>>(x, yb, Wbeta, ln1g, ln1b, h1);
    ff1_gemm<<<dim3(2, 1600), 256, 0, stream>>>(h1, W1, b1, ff1);
    ff2_ln2<<<3200, 256, 0, stream>>>(ff1, W2, b2, h1, ln2g, ln2b, outp);
}

// Round 3
// 843.138 us; speedup vs baseline: 1.2997x; 1.2997x over previous
//
#include <hip/hip_runtime.h>
#include <math.h>

// Problem constants
#define F_DIM 256
#define N_DIM 400
#define C_DIM 128
#define H_DIM 8
#define E_DIM 16
#define ROWS  (F_DIM * N_DIM)          // 102400
#define SBUF  (N_DIM * H_DIM * F_DIM * E_DIM)  // 13107200 floats per q/k/v buffer

typedef _Float16 half2_t __attribute__((ext_vector_type(2)));

// ---------------------------------------------------------------------------
// K0: tree_k = tree_encoding @ W_tree_k ; tree_v = tree_encoding @ W_tree_v
// ---------------------------------------------------------------------------
__global__ __launch_bounds__(256) void tree_proj(
    const float* __restrict__ te, const float* __restrict__ Wtk,
    const float* __restrict__ Wtv, float* __restrict__ tk, float* __restrict__ tv)
{
    int n = blockIdx.x;
    int t = threadIdx.x;
    const float* W = (t < 128) ? Wtk : Wtv;
    float* outp    = (t < 128) ? tk : tv;
    int j = t & 127;
    float acc = 0.f;
    #pragma unroll 4
    for (int c = 0; c < 128; ++c)
        acc += te[n * 128 + c] * W[c * 128 + j];
    outp[n * 128 + j] = acc;
}

// ---------------------------------------------------------------------------
// K1: qkv = x @ W_qkv^T, scatter q/k/v into (n,h,f,e) layout, add tree terms.
// ---------------------------------------------------------------------------
__global__ __launch_bounds__(256) void qkv_gemm(
    const float* __restrict__ x, const float* __restrict__ Wq,
    const float* __restrict__ tk, const float* __restrict__ tv,
    float* __restrict__ qb, float* __restrict__ kb, float* __restrict__ vb)
{
    __shared__ float As[16 * 68];
    __shared__ float Bs[16 * 68];
    int tid = threadIdx.x;
    int bx = blockIdx.x, by = blockIdx.y;
    int ty = tid >> 4, tx = tid & 15;
    float acc[4][4] = {};

    int a_r = tid >> 2;          // 0..63
    int a_k = (tid & 3) * 4;     // 0,4,8,12

    for (int k0 = 0; k0 < 128; k0 += 16) {
        float4 av = *(const float4*)(x  + (by * 64 + a_r) * 128 + k0 + a_k);
        float4 bv = *(const float4*)(Wq + (bx * 64 + a_r) * 128 + k0 + a_k);
        As[(a_k + 0) * 68 + a_r] = av.x;
        As[(a_k + 1) * 68 + a_r] = av.y;
        As[(a_k + 2) * 68 + a_r] = av.z;
        As[(a_k + 3) * 68 + a_r] = av.w;
        Bs[(a_k + 0) * 68 + a_r] = bv.x;
        Bs[(a_k + 1) * 68 + a_r] = bv.y;
        Bs[(a_k + 2) * 68 + a_r] = bv.z;
        Bs[(a_k + 3) * 68 + a_r] = bv.w;
        __syncthreads();
        #pragma unroll
        for (int k = 0; k < 16; ++k) {
            float4 a4 = *(const float4*)(As + k * 68 + ty * 4);
            float4 b4 = *(const float4*)(Bs + k * 68 + tx * 4);
            acc[0][0] += a4.x * b4.x; acc[0][1] += a4.x * b4.y;
            acc[0][2] += a4.x * b4.z; acc[0][3] += a4.x * b4.w;
            acc[1][0] += a4.y * b4.x; acc[1][1] += a4.y * b4.y;
            acc[1][2] += a4.y * b4.z; acc[1][3] += a4.y * b4.w;
            acc[2][0] += a4.z * b4.x; acc[2][1] += a4.z * b4.y;
            acc[2][2] += a4.z * b4.z; acc[2][3] += a4.z * b4.w;
            acc[3][0] += a4.w * b4.x; acc[3][1] += a4.w * b4.y;
            acc[3][2] += a4.w * b4.z; acc[3][3] += a4.w * b4.w;
        }
        __syncthreads();
    }

    #pragma unroll
    for (int i = 0; i < 4; ++i) {
        int r = by * 64 + ty * 4 + i;   // r = f*400 + n
        int f = r / 400;
        int n = r - f * 400;
        #pragma unroll
        for (int j = 0; j < 4; ++j) {
            int o   = bx * 64 + tx * 4 + j;
            int sec = o >> 7;
            int rem = o & 127;
            int h = rem >> 4, e = rem & 15;
            int dst = ((n * 8 + h) * 256 + f) * 16 + e;
            float val = acc[i][j];
            if (sec == 0)       qb[dst] = val;
            else if (sec == 1)  kb[dst] = val + tk[n * 128 + rem];
            else                vb[dst] = val + tv[n * 128 + rem];
        }
    }
}

// ---------------------------------------------------------------------------
// K2: fused attention per (n,h). Thread t owns query row l=t.
// S[l,s] = Q[l].K[s] + (Q[l]+K[s]).emb[clip(l-s)+128]; softmax; out@V.
//
// DPP-rotation: row_l(s+1) == row_{l-1}(s) exactly (incl. clipping), so the
// per-lane emb row lives in registers and is shifted one lane per iteration
// via v_mov_dpp wave_shr:1 (VALU pipe). Only wave-lane-0 needs a fresh row,
// which is wave-uniform -> LDS broadcast. QK and pe dots in fp16 via
// v_dot2_f32_f16 (fp32 accumulate). All in-loop LDS reads are broadcasts.
// LDS: K fp16 8KB + V fp32 16KB + emb fp16 8.2KB = 32.2KB. grid 3200.
// ---------------------------------------------------------------------------
__global__ __launch_bounds__(256) void attn_kernel(
    const float* __restrict__ qb, const float* __restrict__ kb,
    const float* __restrict__ vb, const float* __restrict__ emb,
    float* __restrict__ y)
{
    __shared__ unsigned int Ksh[256 * 8];   // half2-packed K rows
    __shared__ float        Vs [256 * 16];  // fp32 V rows
    __shared__ unsigned int Esh[257 * 8];   // half2-packed emb rows

    int tid = threadIdx.x;
    int bn  = blockIdx.x;           // bn = n*8 + h
    int n   = bn >> 3, h = bn & 7;
    int base = bn * 4096;

    // stage K (fp32 -> fp16 pairs)
    const float4* kg = (const float4*)(kb + base);
    #pragma unroll
    for (int i = 0; i < 4; ++i) {
        float4 f = kg[tid + i * 256];
        half2_t h01 = { (_Float16)f.x, (_Float16)f.y };
        half2_t h23 = { (_Float16)f.z, (_Float16)f.w };
        Ksh[(tid + i * 256) * 2 + 0] = __builtin_bit_cast(unsigned int, h01);
        Ksh[(tid + i * 256) * 2 + 1] = __builtin_bit_cast(unsigned int, h23);
    }
    // stage V (fp32)
    const float4* vg = (const float4*)(vb + base);
    float4* V4 = (float4*)Vs;
    #pragma unroll
    for (int i = 0; i < 4; ++i) V4[tid + i * 256] = vg[tid + i * 256];
    // stage emb (fp32 -> fp16 pairs); 257*16 floats = 2056 float2
    const float2* eg = (const float2*)emb;
    for (int i = tid; i < 257 * 8; i += 256) {
        float2 f = eg[i];
        half2_t hh = { (_Float16)f.x, (_Float16)f.y };
        Esh[i] = __builtin_bit_cast(unsigned int, hh);
    }

    // per-lane q in fp16 pairs
    half2_t q2[8];
    {
        const float4* qg = (const float4*)(qb + base + tid * 16);
        #pragma unroll
        for (int i = 0; i < 4; ++i) {
            float4 f = qg[i];
            q2[i * 2 + 0] = half2_t{ (_Float16)f.x, (_Float16)f.y };
            q2[i * 2 + 1] = half2_t{ (_Float16)f.z, (_Float16)f.w };
        }
    }
    __syncthreads();

    int  l     = tid;
    int  w64   = tid & 192;              // wave base lane (tid>>6)*64
    bool lane0 = ((tid & 63) == 0);

    // init er = emb row clip(l-0)+128 = min(l,128)+128 (one-time lane gather)
    half2_t er[8];
    {
        int r0 = (l > 128 ? 128 : l) + 128;
        const uint4* ep = (const uint4*)(Esh + r0 * 8);
        uint4 a = ep[0], b4 = ep[1];
        er[0] = __builtin_bit_cast(half2_t, a.x);
        er[1] = __builtin_bit_cast(half2_t, a.y);
        er[2] = __builtin_bit_cast(half2_t, a.z);
        er[3] = __builtin_bit_cast(half2_t, a.w);
        er[4] = __builtin_bit_cast(half2_t, b4.x);
        er[5] = __builtin_bit_cast(half2_t, b4.y);
        er[6] = __builtin_bit_cast(half2_t, b4.z);
        er[7] = __builtin_bit_cast(half2_t, b4.w);
    }

    float o[16];
    #pragma unroll
    for (int i = 0; i < 16; ++i) o[i] = 0.f;
    float denom = 0.f;

    for (int s = 0; s < 256; ++s) {
        // broadcast K row (fp16 pairs)
        const uint4* kp = (const uint4*)(Ksh + s * 8);
        uint4 ka = kp[0], kb4 = kp[1];
        unsigned int kw[8] = { ka.x, ka.y, ka.z, ka.w, kb4.x, kb4.y, kb4.z, kb4.w };

        float s1 = 0.f, s2 = 0.f;
        #pragma unroll
        for (int e = 0; e < 8; ++e) {
            half2_t kk = __builtin_bit_cast(half2_t, kw[e]);
            s1 = __builtin_amdgcn_fdot2(q2[e], kk, s1, false);
            half2_t qk = q2[e] + kk;
            s2 = __builtin_amdgcn_fdot2(qk, er[e], s2, false);
        }
        float p = __expf((s1 + s2) * 0.25f);
        denom += p;

        // broadcast V row (fp32), accumulate
        const float4* vp = (const float4*)(Vs + s * 16);
        #pragma unroll
        for (int g = 0; g < 4; ++g) {
            float4 vv = vp[g];
            o[g * 4 + 0] += p * vv.x;
            o[g * 4 + 1] += p * vv.y;
            o[g * 4 + 2] += p * vv.z;
            o[g * 4 + 3] += p * vv.w;
        }

        // rotate er one lane right; wave-lane-0 takes the fresh boundary row
        int b = w64 - s - 1;
        b = b < -128 ? -128 : (b > 128 ? 128 : b);
        b += 128;
        const uint4* bp = (const uint4*)(Esh + b * 8);   // wave-uniform -> broadcast
        uint4 b0 = bp[0], b1 = bp[1];
        unsigned int bw[8] = { b0.x, b0.y, b0.z, b0.w, b1.x, b1.y, b1.z, b1.w };
        #pragma unroll
        for (int e = 0; e < 8; ++e) {
            int cur = __builtin_bit_cast(int, er[e]);
            int sh  = __builtin_amdgcn_update_dpp(cur, cur, 0x138, 0xF, 0xF, false); // wave_shr:1
            int nw  = lane0 ? (int)bw[e] : sh;
            er[e] = __builtin_bit_cast(half2_t, nw);
        }
    }

    float inv = 1.0f / denom;
    float* yo = y + (l * 400 + n) * 128 + h * 16;
    float4* yo4 = (float4*)yo;
    yo4[0] = make_float4(o[0]*inv,  o[1]*inv,  o[2]*inv,  o[3]*inv);
    yo4[1] = make_float4(o[4]*inv,  o[5]*inv,  o[6]*inv,  o[7]*inv);
    yo4[2] = make_float4(o[8]*inv,  o[9]*inv,  o[10]*inv, o[11]*inv);
    yo4[3] = make_float4(o[12]*inv, o[13]*inv, o[14]*inv, o[15]*inv);
}

// ---------------------------------------------------------------------------
// K3: gate = sigmoid([y,x,y-x]@W_beta^T); z = g*x+(1-g)*y; h1 = LN1(z)
// ---------------------------------------------------------------------------
__global__ __launch_bounds__(128) void gate_ln1(
    const float* __restrict__ x, const float* __restrict__ y,
    const float* __restrict__ Wb, const float* __restrict__ g,
    const float* __restrict__ b, float* __restrict__ h1)
{
    __shared__ float sred[4];
    int r = blockIdx.x, c = threadIdx.x;
    float xv = x[r * 128 + c];
    float yv = y[r * 128 + c];
    float sv = yv * Wb[c] + xv * Wb[128 + c] + (yv - xv) * Wb[256 + c];
    int wid = c >> 6, lane = c & 63;
    #pragma unroll
    for (int off = 32; off > 0; off >>= 1) sv += __shfl_down(sv, off);
    if (lane == 0) sred[wid] = sv;
    __syncthreads();
    float total = sred[0] + sred[1];
    float gate = 1.0f / (1.0f + __expf(-total));
    float z = gate * xv + (1.0f - gate) * yv;

    float z1 = z, z2 = z * z;
    #pragma unroll
    for (int off = 32; off > 0; off >>= 1) {
        z1 += __shfl_down(z1, off);
        z2 += __shfl_down(z2, off);
    }
    __syncthreads();   // protect sred reuse
    if (lane == 0) { sred[wid] = z1; sred[2 + wid] = z2; }
    __syncthreads();
    float S1 = sred[0] + sred[1];
    float S2 = sred[2] + sred[3];
    float mu  = S1 * (1.0f / 128.0f);
    float var = S2 * (1.0f / 128.0f) - mu * mu;
    float rs  = rsqrtf(var + 1e-5f);
    h1[r * 128 + c] = (z - mu) * rs * g[c] + b[c];
}

// ---------------------------------------------------------------------------
// K4: ff1 = gelu_exact(h1 @ W1^T + b1)
// ---------------------------------------------------------------------------
__global__ __launch_bounds__(256) void ff1_gemm(
    const float* __restrict__ A, const float* __restrict__ W,
    const float* __restrict__ bias, float* __restrict__ outp)
{
    __shared__ float As[16 * 68];
    __shared__ float Bs[16 * 68];
    int tid = threadIdx.x;
    int bx = blockIdx.x, by = blockIdx.y;
    int ty = tid >> 4, tx = tid & 15;
    float acc[4][4] = {};
    int a_r = tid >> 2;
    int a_k = (tid & 3) * 4;

    for (int k0 = 0; k0 < 128; k0 += 16) {
        float4 av = *(const float4*)(A + (by * 64 + a_r) * 128 + k0 + a_k);
        float4 bv = *(const float4*)(W + (bx * 64 + a_r) * 128 + k0 + a_k);
        As[(a_k + 0) * 68 + a_r] = av.x;
        As[(a_k + 1) * 68 + a_r] = av.y;
        As[(a_k + 2) * 68 + a_r] = av.z;
        As[(a_k + 3) * 68 + a_r] = av.w;
        Bs[(a_k + 0) * 68 + a_r] = bv.x;
        Bs[(a_k + 1) * 68 + a_r] = bv.y;
        Bs[(a_k + 2) * 68 + a_r] = bv.z;
        Bs[(a_k + 3) * 68 + a_r] = bv.w;
        __syncthreads();
        #pragma unroll
        for (int k = 0; k < 16; ++k) {
            float4 a4 = *(const float4*)(As + k * 68 + ty * 4);
            float4 b4 = *(const float4*)(Bs + k * 68 + tx * 4);
            acc[0][0] += a4.x * b4.x; acc[0][1] += a4.x * b4.y;
            acc[0][2] += a4.x * b4.z; acc[0][3] += a4.x * b4.w;
            acc[1][0] += a4.y * b4.x; acc[1][1] += a4.y * b4.y;
            acc[1][2] += a4.y * b4.z; acc[1][3] += a4.y * b4.w;
            acc[2][0] += a4.z * b4.x; acc[2][1] += a4.z * b4.y;
            acc[2][2] += a4.z * b4.z; acc[2][3] += a4.z * b4.w;
            acc[3][0] += a4.w * b4.x; acc[3][1] += a4.w * b4.y;
            acc[3][2] += a4.w * b4.z; acc[3][3] += a4.w * b4.w;
        }
        __syncthreads();
    }
    #pragma unroll
    for (int i = 0; i < 4; ++i) {
        int r = by * 64 + ty * 4 + i;
        #pragma unroll
        for (int j = 0; j < 4; ++j) {
            int o = bx * 64 + tx * 4 + j;
            float v = acc[i][j] + bias[o];
            v = 0.5f * v * (1.0f + erff(v * 0.70710678118654752f));  // exact GELU
            outp[r * 128 + o] = v;
        }
    }
}

// ---------------------------------------------------------------------------
// K5: out = LN2(ff1 @ W2^T + b2 + h1)
// ---------------------------------------------------------------------------
__global__ __launch_bounds__(256) void ff2_ln2(
    const float* __restrict__ A, const float* __restrict__ W2,
    const float* __restrict__ b2, const float* __restrict__ h1,
    const float* __restrict__ g, const float* __restrict__ bb,
    float* __restrict__ outp)
{
    __shared__ float As[16 * 36];
    __shared__ float Bs[16 * 132];
    int tid = threadIdx.x;
    int by = blockIdx.x;
    int ty = tid >> 5, tx = tid & 31;
    float acc[4][4] = {};

    for (int k0 = 0; k0 < 128; k0 += 16) {
        if (tid < 128) {
            int a_r = tid >> 2;          // 0..31
            int a_k = (tid & 3) * 4;
            float4 av = *(const float4*)(A + (by * 32 + a_r) * 128 + k0 + a_k);
            As[(a_k + 0) * 36 + a_r] = av.x;
            As[(a_k + 1) * 36 + a_r] = av.y;
            As[(a_k + 2) * 36 + a_r] = av.z;
            As[(a_k + 3) * 36 + a_r] = av.w;
        }
        {
            int b_j = tid >> 1;          // 0..127
            int b_k = (tid & 1) * 8;
            float4 b0 = *(const float4*)(W2 + b_j * 128 + k0 + b_k);
            float4 b1 = *(const float4*)(W2 + b_j * 128 + k0 + b_k + 4);
            Bs[(b_k + 0) * 132 + b_j] = b0.x;
            Bs[(b_k + 1) * 132 + b_j] = b0.y;
            Bs[(b_k + 2) * 132 + b_j] = b0.z;
            Bs[(b_k + 3) * 132 + b_j] = b0.w;
            Bs[(b_k + 4) * 132 + b_j] = b1.x;
            Bs[(b_k + 5) * 132 + b_j] = b1.y;
            Bs[(b_k + 6) * 132 + b_j] = b1.z;
            Bs[(b_k + 7) * 132 + b_j] = b1.w;
        }
        __syncthreads();
        #pragma unroll
        for (int k = 0; k < 16; ++k) {
            float4 a4 = *(const float4*)(As + k * 36 + ty * 4);
            float4 b4 = *(const float4*)(Bs + k * 132 + tx * 4);
            acc[0][0] += a4.x * b4.x; acc[0][1] += a4.x * b4.y;
            acc[0][2] += a4.x * b4.z; acc[0][3] += a4.x * b4.w;
            acc[1][0] += a4.y * b4.x; acc[1][1] += a4.y * b4.y;
            acc[1][2] += a4.y * b4.z; acc[1][3] += a4.y * b4.w;
            acc[2][0] += a4.z * b4.x; acc[2][1] += a4.z * b4.y;
            acc[2][2] += a4.z * b4.z; acc[2][3] += a4.z * b4.w;
            acc[3][0] += a4.w * b4.x; acc[3][1] += a4.w * b4.y;
            acc[3][2] += a4.w * b4.z; acc[3][3] += a4.w * b4.w;
        }
        __syncthreads();
    }

    float4 bias4 = *(const float4*)(b2 + tx * 4);
    float4 g4    = *(const float4*)(g  + tx * 4);
    float4 bb4   = *(const float4*)(bb + tx * 4);
    float z[4][4];
    float s1[4], s2[4];
    #pragma unroll
    for (int i = 0; i < 4; ++i) {
        int r = by * 32 + ty * 4 + i;
        float4 hv = *(const float4*)(h1 + r * 128 + tx * 4);
        z[i][0] = acc[i][0] + bias4.x + hv.x;
        z[i][1] = acc[i][1] + bias4.y + hv.y;
        z[i][2] = acc[i][2] + bias4.z + hv.z;
        z[i][3] = acc[i][3] + bias4.w + hv.w;
        s1[i] = z[i][0] + z[i][1] + z[i][2] + z[i][3];
        s2[i] = z[i][0]*z[i][0] + z[i][1]*z[i][1] + z[i][2]*z[i][2] + z[i][3]*z[i][3];
    }
    #pragma unroll
    for (int off = 16; off > 0; off >>= 1) {
        #pragma unroll
        for (int i = 0; i < 4; ++i) {
            s1[i] += __shfl_xor(s1[i], off);
            s2[i] += __shfl_xor(s2[i], off);
        }
    }
    #pragma unroll
    for (int i = 0; i < 4; ++i) {
        int r = by * 32 + ty * 4 + i;
        float mu  = s1[i] * (1.0f / 128.0f);
        float var = s2[i] * (1.0f / 128.0f) - mu * mu;
        float rs  = rsqrtf(var + 1e-5f);
        float4 ov;
        ov.x = (z[i][0] - mu) * rs * g4.x + bb4.x;
        ov.y = (z[i][1] - mu) * rs * g4.y + bb4.y;
        ov.z = (z[i][2] - mu) * rs * g4.z + bb4.z;
        ov.w = (z[i][3] - mu) * rs * g4.w + bb4.w;
        *(float4*)(outp + r * 128 + tx * 4) = ov;
    }
}

// ---------------------------------------------------------------------------
extern "C" void kernel_launch(void* const* d_in, const int* in_sizes, int n_in,
                              void* d_out, int out_size, void* d_ws, size_t ws_size,
                              hipStream_t stream)
{
    const float* x     = (const float*)d_in[0];
    const float* te    = (const float*)d_in[1];
    const float* Wqkv  = (const float*)d_in[2];
    const float* Wtk   = (const float*)d_in[3];
    const float* Wtv   = (const float*)d_in[4];
    const float* emb   = (const float*)d_in[5];
    const float* Wbeta = (const float*)d_in[6];
    const float* ln1g  = (const float*)d_in[7];
    const float* ln1b  = (const float*)d_in[8];
    const float* ln2g  = (const float*)d_in[9];
    const float* ln2b  = (const float*)d_in[10];
    const float* W1    = (const float*)d_in[11];
    const float* b1    = (const float*)d_in[12];
    const float* W2    = (const float*)d_in[13];
    const float* b2    = (const float*)d_in[14];
    float* outp = (float*)d_out;

    float* ws = (float*)d_ws;
    float* tk = ws;                       // 51200
    float* tv = ws + 51200;               // 51200
    float* qb = ws + 102400;              // SBUF
    float* kb = qb + SBUF;                // SBUF
    float* vb = kb + SBUF;                // SBUF
    float* yb = vb + SBUF;                // SBUF  (f,n,c)
    float* h1 = kb;                       // reuse: k dead after attention
    float* ff1 = qb;                      // reuse: q dead after attention

    tree_proj<<<400, 256, 0, stream>>>(te, Wtk, Wtv, tk, tv);
    qkv_gemm<<<dim3(6, 1600), 256, 0, stream>>>(x, Wqkv, tk, tv, qb, kb, vb);
    attn_kernel<<<3200, 256, 0, stream>>>(qb, kb, vb, emb, yb);
    gate_ln1<<<ROWS, 128, 0, stream>>>(x, yb, Wbeta, ln1g, ln1b, h1);
    ff1_gemm<<<dim3(2, 1600), 256, 0, stream>>>(h1, W1, b1, ff1);
    ff2_ln2<<<3200, 256, 0, stream>>>(ff1, W2, b2, h1, ln2g, ln2b, outp);
}

// Round 5
// 801.364 us; speedup vs baseline: 1.3675x; 1.0521x over previous
//
#include <hip/hip_runtime.h>
#include <math.h>

// Problem constants
#define F_DIM 256
#define N_DIM 400
#define C_DIM 128
#define H_DIM 8
#define E_DIM 16
#define ROWS  (F_DIM * N_DIM)          // 102400
#define SBUF  (N_DIM * H_DIM * F_DIM * E_DIM)  // 13107200 floats per q/k/v buffer

typedef _Float16 half2_t __attribute__((ext_vector_type(2)));
typedef _Float16 f16x8   __attribute__((ext_vector_type(8)));
typedef float    f32x16  __attribute__((ext_vector_type(16)));

struct H2x4 { half2_t h[4]; };

// pack 8 consecutive fp32 (two float4) into an f16x8 fragment
// (cvt_pkrtz returns __fp16x2; bit_cast to our _Float16x2)
__device__ inline f16x8 pack8(float4 a, float4 b) {
    H2x4 t;
    t.h[0] = __builtin_bit_cast(half2_t, __builtin_amdgcn_cvt_pkrtz(a.x, a.y));
    t.h[1] = __builtin_bit_cast(half2_t, __builtin_amdgcn_cvt_pkrtz(a.z, a.w));
    t.h[2] = __builtin_bit_cast(half2_t, __builtin_amdgcn_cvt_pkrtz(b.x, b.y));
    t.h[3] = __builtin_bit_cast(half2_t, __builtin_amdgcn_cvt_pkrtz(b.z, b.w));
    return __builtin_bit_cast(f16x8, t);
}

// ---------------------------------------------------------------------------
// K0: tree_k = tree_encoding @ W_tree_k ; tree_v = tree_encoding @ W_tree_v
// ---------------------------------------------------------------------------
__global__ __launch_bounds__(256) void tree_proj(
    const float* __restrict__ te, const float* __restrict__ Wtk,
    const float* __restrict__ Wtv, float* __restrict__ tk, float* __restrict__ tv)
{
    int n = blockIdx.x;
    int t = threadIdx.x;
    const float* W = (t < 128) ? Wtk : Wtv;
    float* outp    = (t < 128) ? tk : tv;
    int j = t & 127;
    float acc = 0.f;
    #pragma unroll 4
    for (int c = 0; c < 128; ++c)
        acc += te[n * 128 + c] * W[c * 128 + j];
    outp[n * 128 + j] = acc;
}

// ---------------------------------------------------------------------------
// K1: qkv = x @ W_qkv^T via fp16 MFMA 32x32x16, scatter to (n,h,f,e) + tree.
// Block 256 = 4 waves; block tile 64 rows x 64 cols; wave tile 32x32.
// Frags loaded straight from global (fp32) + cvt_pkrtz; no LDS, no barriers.
// A[m=lane&31][k=8*(lane>>5)+j]; B[k][n=lane&31];
// C: col=lane&31, row=(reg&3)+8*(reg>>2)+4*(lane>>5).
// grid (6, 1600)
// ---------------------------------------------------------------------------
__global__ __launch_bounds__(256) void qkv_gemm(
    const float* __restrict__ x, const float* __restrict__ Wq,
    const float* __restrict__ tk, const float* __restrict__ tv,
    float* __restrict__ qb, float* __restrict__ kb, float* __restrict__ vb)
{
    int tid  = threadIdx.x;
    int wave = tid >> 6, lane = tid & 63;
    int m32  = lane & 31, khalf = lane >> 5;
    int row0 = blockIdx.y * 64 + (wave & 1) * 32;
    int col0 = blockIdx.x * 64 + (wave >> 1) * 32;

    const float* xp = x  + (row0 + m32) * 128 + khalf * 8;
    const float* wp = Wq + (col0 + m32) * 128 + khalf * 8;

    f32x16 acc;
    #pragma unroll
    for (int i = 0; i < 16; ++i) acc[i] = 0.f;

    #pragma unroll
    for (int k0 = 0; k0 < 128; k0 += 16) {
        float4 xa = *(const float4*)(xp + k0);
        float4 xb = *(const float4*)(xp + k0 + 4);
        float4 wa = *(const float4*)(wp + k0);
        float4 wb = *(const float4*)(wp + k0 + 4);
        f16x8 af = pack8(xa, xb);
        f16x8 bf = pack8(wa, wb);
        acc = __builtin_amdgcn_mfma_f32_32x32x16_f16(af, bf, acc, 0, 0, 0);
    }

    // epilogue: scatter; section uniform per block (64-col tiles align in 128)
    int o   = col0 + m32;
    int sec = o >> 7;
    int rem = o & 127;
    int h = rem >> 4, e = rem & 15;
    #pragma unroll
    for (int reg = 0; reg < 16; ++reg) {
        int r = row0 + (reg & 3) + 8 * (reg >> 2) + 4 * khalf;  // r = f*400+n
        int f = r / 400;
        int n = r - f * 400;
        int dst = ((n * 8 + h) * 256 + f) * 16 + e;
        float val = acc[reg];
        if (sec == 0)       qb[dst] = val;
        else if (sec == 1)  kb[dst] = val + tk[n * 128 + rem];
        else                vb[dst] = val + tv[n * 128 + rem];
    }
}

// ---------------------------------------------------------------------------
// K2: fused attention per (n,h) — unchanged from round 3 (422 us, scalar).
// ---------------------------------------------------------------------------
__global__ __launch_bounds__(256) void attn_kernel(
    const float* __restrict__ qb, const float* __restrict__ kb,
    const float* __restrict__ vb, const float* __restrict__ emb,
    float* __restrict__ y)
{
    __shared__ unsigned int Ksh[256 * 8];   // half2-packed K rows
    __shared__ float        Vs [256 * 16];  // fp32 V rows
    __shared__ unsigned int Esh[257 * 8];   // half2-packed emb rows

    int tid = threadIdx.x;
    int bn  = blockIdx.x;           // bn = n*8 + h
    int n   = bn >> 3, h = bn & 7;
    int base = bn * 4096;

    const float4* kg = (const float4*)(kb + base);
    #pragma unroll
    for (int i = 0; i < 4; ++i) {
        float4 f = kg[tid + i * 256];
        half2_t h01 = { (_Float16)f.x, (_Float16)f.y };
        half2_t h23 = { (_Float16)f.z, (_Float16)f.w };
        Ksh[(tid + i * 256) * 2 + 0] = __builtin_bit_cast(unsigned int, h01);
        Ksh[(tid + i * 256) * 2 + 1] = __builtin_bit_cast(unsigned int, h23);
    }
    const float4* vg = (const float4*)(vb + base);
    float4* V4 = (float4*)Vs;
    #pragma unroll
    for (int i = 0; i < 4; ++i) V4[tid + i * 256] = vg[tid + i * 256];
    const float2* eg = (const float2*)emb;
    for (int i = tid; i < 257 * 8; i += 256) {
        float2 f = eg[i];
        half2_t hh = { (_Float16)f.x, (_Float16)f.y };
        Esh[i] = __builtin_bit_cast(unsigned int, hh);
    }

    half2_t q2[8];
    {
        const float4* qg = (const float4*)(qb + base + tid * 16);
        #pragma unroll
        for (int i = 0; i < 4; ++i) {
            float4 f = qg[i];
            q2[i * 2 + 0] = half2_t{ (_Float16)f.x, (_Float16)f.y };
            q2[i * 2 + 1] = half2_t{ (_Float16)f.z, (_Float16)f.w };
        }
    }
    __syncthreads();

    int  l     = tid;
    int  w64   = tid & 192;
    bool lane0 = ((tid & 63) == 0);

    half2_t er[8];
    {
        int r0 = (l > 128 ? 128 : l) + 128;
        const uint4* ep = (const uint4*)(Esh + r0 * 8);
        uint4 a = ep[0], b4 = ep[1];
        er[0] = __builtin_bit_cast(half2_t, a.x);
        er[1] = __builtin_bit_cast(half2_t, a.y);
        er[2] = __builtin_bit_cast(half2_t, a.z);
        er[3] = __builtin_bit_cast(half2_t, a.w);
        er[4] = __builtin_bit_cast(half2_t, b4.x);
        er[5] = __builtin_bit_cast(half2_t, b4.y);
        er[6] = __builtin_bit_cast(half2_t, b4.z);
        er[7] = __builtin_bit_cast(half2_t, b4.w);
    }

    float o[16];
    #pragma unroll
    for (int i = 0; i < 16; ++i) o[i] = 0.f;
    float denom = 0.f;

    for (int s = 0; s < 256; ++s) {
        const uint4* kp = (const uint4*)(Ksh + s * 8);
        uint4 ka = kp[0], kb4 = kp[1];
        unsigned int kw[8] = { ka.x, ka.y, ka.z, ka.w, kb4.x, kb4.y, kb4.z, kb4.w };

        float s1 = 0.f, s2 = 0.f;
        #pragma unroll
        for (int e = 0; e < 8; ++e) {
            half2_t kk = __builtin_bit_cast(half2_t, kw[e]);
            s1 = __builtin_amdgcn_fdot2(q2[e], kk, s1, false);
            half2_t qk = q2[e] + kk;
            s2 = __builtin_amdgcn_fdot2(qk, er[e], s2, false);
        }
        float p = __expf((s1 + s2) * 0.25f);
        denom += p;

        const float4* vp = (const float4*)(Vs + s * 16);
        #pragma unroll
        for (int g = 0; g < 4; ++g) {
            float4 vv = vp[g];
            o[g * 4 + 0] += p * vv.x;
            o[g * 4 + 1] += p * vv.y;
            o[g * 4 + 2] += p * vv.z;
            o[g * 4 + 3] += p * vv.w;
        }

        int b = w64 - s - 1;
        b = b < -128 ? -128 : (b > 128 ? 128 : b);
        b += 128;
        const uint4* bp = (const uint4*)(Esh + b * 8);
        uint4 b0 = bp[0], b1 = bp[1];
        unsigned int bw[8] = { b0.x, b0.y, b0.z, b0.w, b1.x, b1.y, b1.z, b1.w };
        #pragma unroll
        for (int e = 0; e < 8; ++e) {
            int cur = __builtin_bit_cast(int, er[e]);
            int sh  = __builtin_amdgcn_update_dpp(cur, cur, 0x138, 0xF, 0xF, false); // wave_shr:1
            int nw  = lane0 ? (int)bw[e] : sh;
            er[e] = __builtin_bit_cast(half2_t, nw);
        }
    }

    float inv = 1.0f / denom;
    float* yo = y + (l * 400 + n) * 128 + h * 16;
    float4* yo4 = (float4*)yo;
    yo4[0] = make_float4(o[0]*inv,  o[1]*inv,  o[2]*inv,  o[3]*inv);
    yo4[1] = make_float4(o[4]*inv,  o[5]*inv,  o[6]*inv,  o[7]*inv);
    yo4[2] = make_float4(o[8]*inv,  o[9]*inv,  o[10]*inv, o[11]*inv);
    yo4[3] = make_float4(o[12]*inv, o[13]*inv, o[14]*inv, o[15]*inv);
}

// ---------------------------------------------------------------------------
// K3: gate+LN1, wave-per-row (64 lanes x 2 cols), no LDS, no barriers.
// Block 256 = 4 rows; grid 25600.
// ---------------------------------------------------------------------------
__global__ __launch_bounds__(256) void gate_ln1(
    const float* __restrict__ x, const float* __restrict__ y,
    const float* __restrict__ Wb, const float* __restrict__ g,
    const float* __restrict__ b, float* __restrict__ h1)
{
    int tid  = threadIdx.x;
    int r    = blockIdx.x * 4 + (tid >> 6);
    int lane = tid & 63;
    int c    = lane * 2;

    float2 xv = *(const float2*)(x + r * 128 + c);
    float2 yv = *(const float2*)(y + r * 128 + c);
    float2 w0 = *(const float2*)(Wb + c);
    float2 w1 = *(const float2*)(Wb + 128 + c);
    float2 w2 = *(const float2*)(Wb + 256 + c);

    float sv = yv.x * w0.x + yv.y * w0.y
             + xv.x * w1.x + xv.y * w1.y
             + (yv.x - xv.x) * w2.x + (yv.y - xv.y) * w2.y;
    #pragma unroll
    for (int off = 32; off > 0; off >>= 1) sv += __shfl_xor(sv, off);
    float gate = 1.0f / (1.0f + __expf(-sv));

    float z0 = gate * xv.x + (1.0f - gate) * yv.x;
    float z1 = gate * xv.y + (1.0f - gate) * yv.y;
    float s1 = z0 + z1, s2 = z0 * z0 + z1 * z1;
    #pragma unroll
    for (int off = 32; off > 0; off >>= 1) {
        s1 += __shfl_xor(s1, off);
        s2 += __shfl_xor(s2, off);
    }
    float mu  = s1 * (1.0f / 128.0f);
    float var = s2 * (1.0f / 128.0f) - mu * mu;
    float rs  = rsqrtf(var + 1e-5f);

    float2 gv = *(const float2*)(g + c);
    float2 bv = *(const float2*)(b + c);
    float2 ov;
    ov.x = (z0 - mu) * rs * gv.x + bv.x;
    ov.y = (z1 - mu) * rs * gv.y + bv.y;
    *(float2*)(h1 + r * 128 + c) = ov;
}

// ---------------------------------------------------------------------------
// K4: ff1 = gelu_exact(h1 @ W1^T + b1) via fp16 MFMA. Same scheme as K1.
// grid (2, 1600); block tile 64x64.
// ---------------------------------------------------------------------------
__global__ __launch_bounds__(256) void ff1_gemm(
    const float* __restrict__ A, const float* __restrict__ W,
    const float* __restrict__ bias, float* __restrict__ outp)
{
    int tid  = threadIdx.x;
    int wave = tid >> 6, lane = tid & 63;
    int m32  = lane & 31, khalf = lane >> 5;
    int row0 = blockIdx.y * 64 + (wave & 1) * 32;
    int col0 = blockIdx.x * 64 + (wave >> 1) * 32;

    const float* ap = A + (row0 + m32) * 128 + khalf * 8;
    const float* wp = W + (col0 + m32) * 128 + khalf * 8;

    f32x16 acc;
    #pragma unroll
    for (int i = 0; i < 16; ++i) acc[i] = 0.f;

    #pragma unroll
    for (int k0 = 0; k0 < 128; k0 += 16) {
        float4 aa = *(const float4*)(ap + k0);
        float4 ab = *(const float4*)(ap + k0 + 4);
        float4 wa = *(const float4*)(wp + k0);
        float4 wb = *(const float4*)(wp + k0 + 4);
        acc = __builtin_amdgcn_mfma_f32_32x32x16_f16(pack8(aa, ab), pack8(wa, wb), acc, 0, 0, 0);
    }

    int   c  = col0 + m32;
    float bi = bias[c];
    #pragma unroll
    for (int reg = 0; reg < 16; ++reg) {
        int r = row0 + (reg & 3) + 8 * (reg >> 2) + 4 * khalf;
        float v = acc[reg] + bi;
        v = 0.5f * v * (1.0f + erff(v * 0.70710678118654752f));  // exact GELU
        outp[r * 128 + c] = v;
    }
}

// ---------------------------------------------------------------------------
// K5: out = LN2(ff1 @ W2^T + b2 + h1) via fp16 MFMA.
// Block 256 = 4 waves; 32 rows x 128 cols (wave w -> col tile w*32).
// MFMA tiles -> LDS -> row-wise LN (8 lanes/row, shfl within wave).
// grid 3200.
// ---------------------------------------------------------------------------
__global__ __launch_bounds__(256) void ff2_ln2(
    const float* __restrict__ A, const float* __restrict__ W2,
    const float* __restrict__ b2, const float* __restrict__ h1,
    const float* __restrict__ g, const float* __restrict__ bb,
    float* __restrict__ outp)
{
    __shared__ float Cs[32 * 132];
    int tid  = threadIdx.x;
    int wave = tid >> 6, lane = tid & 63;
    int m32  = lane & 31, khalf = lane >> 5;
    int row0 = blockIdx.x * 32;
    int col0 = wave * 32;

    const float* ap = A  + (row0 + m32) * 128 + khalf * 8;
    const float* wp = W2 + (col0 + m32) * 128 + khalf * 8;

    f32x16 acc;
    #pragma unroll
    for (int i = 0; i < 16; ++i) acc[i] = 0.f;

    #pragma unroll
    for (int k0 = 0; k0 < 128; k0 += 16) {
        float4 aa = *(const float4*)(ap + k0);
        float4 ab = *(const float4*)(ap + k0 + 4);
        float4 wa = *(const float4*)(wp + k0);
        float4 wb = *(const float4*)(wp + k0 + 4);
        acc = __builtin_amdgcn_mfma_f32_32x32x16_f16(pack8(aa, ab), pack8(wa, wb), acc, 0, 0, 0);
    }

    #pragma unroll
    for (int reg = 0; reg < 16; ++reg) {
        int rloc = (reg & 3) + 8 * (reg >> 2) + 4 * khalf;
        Cs[rloc * 132 + col0 + m32] = acc[reg];
    }
    __syncthreads();

    // LN phase: thread t -> row t>>3, col segment (t&7)*16
    int rloc = tid >> 3, seg = (tid & 7) * 16;
    int r = row0 + rloc;
    float z[16];
    float s1 = 0.f, s2 = 0.f;
    #pragma unroll
    for (int j4 = 0; j4 < 4; ++j4) {
        float4 cv = *(const float4*)(Cs + rloc * 132 + seg + j4 * 4);
        float4 hv = *(const float4*)(h1 + r * 128 + seg + j4 * 4);
        float4 bv = *(const float4*)(b2 + seg + j4 * 4);
        z[j4*4+0] = cv.x + bv.x + hv.x;
        z[j4*4+1] = cv.y + bv.y + hv.y;
        z[j4*4+2] = cv.z + bv.z + hv.z;
        z[j4*4+3] = cv.w + bv.w + hv.w;
        s1 += z[j4*4+0] + z[j4*4+1] + z[j4*4+2] + z[j4*4+3];
        s2 += z[j4*4+0]*z[j4*4+0] + z[j4*4+1]*z[j4*4+1]
            + z[j4*4+2]*z[j4*4+2] + z[j4*4+3]*z[j4*4+3];
    }
    // 8 lanes per row are consecutive lanes within a wave
    #pragma unroll
    for (int off = 4; off > 0; off >>= 1) {
        s1 += __shfl_xor(s1, off);
        s2 += __shfl_xor(s2, off);
    }
    float mu  = s1 * (1.0f / 128.0f);
    float var = s2 * (1.0f / 128.0f) - mu * mu;
    float rs  = rsqrtf(var + 1e-5f);
    #pragma unroll
    for (int j4 = 0; j4 < 4; ++j4) {
        float4 gv = *(const float4*)(g  + seg + j4 * 4);
        float4 bv = *(const float4*)(bb + seg + j4 * 4);
        float4 ov;
        ov.x = (z[j4*4+0] - mu) * rs * gv.x + bv.x;
        ov.y = (z[j4*4+1] - mu) * rs * gv.y + bv.y;
        ov.z = (z[j4*4+2] - mu) * rs * gv.z + bv.z;
        ov.w = (z[j4*4+3] - mu) * rs * gv.w + bv.w;
        *(float4*)(outp + r * 128 + seg + j4 * 4) = ov;
    }
}

// ---------------------------------------------------------------------------
extern "C" void kernel_launch(void* const* d_in, const int* in_sizes, int n_in,
                              void* d_out, int out_size, void* d_ws, size_t ws_size,
                              hipStream_t stream)
{
    const float* x     = (const float*)d_in[0];
    const float* te    = (const float*)d_in[1];
    const float* Wqkv  = (const float*)d_in[2];
    const float* Wtk   = (const float*)d_in[3];
    const float* Wtv   = (const float*)d_in[4];
    const float* emb   = (const float*)d_in[5];
    const float* Wbeta = (const float*)d_in[6];
    const float* ln1g  = (const float*)d_in[7];
    const float* ln1b  = (const float*)d_in[8];
    const float* ln2g  = (const float*)d_in[9];
    const float* ln2b  = (const float*)d_in[10];
    const float* W1    = (const float*)d_in[11];
    const float* b1    = (const float*)d_in[12];
    const float* W2    = (const float*)d_in[13];
    const float* b2    = (const float*)d_in[14];
    float* outp = (float*)d_out;

    float* ws = (float*)d_ws;
    float* tk = ws;                       // 51200
    float* tv = ws + 51200;               // 51200
    float* qb = ws + 102400;              // SBUF
    float* kb = qb + SBUF;                // SBUF
    float* vb = kb + SBUF;                // SBUF
    float* yb = vb + SBUF;                // SBUF  (f,n,c)
    float* h1 = kb;                       // reuse: k dead after attention
    float* ff1 = qb;                      // reuse: q dead after attention

    tree_proj<<<400, 256, 0, stream>>>(te, Wtk, Wtv, tk, tv);
    qkv_gemm<<<dim3(6, 1600), 256, 0, stream>>>(x, Wqkv, tk, tv, qb, kb, vb);
    attn_kernel<<<3200, 256, 0, stream>>>(qb, kb, vb, emb, yb);
    gate_ln1<<<ROWS / 4, 256, 0, stream>>>(x, yb, Wbeta, ln1g, ln1b, h1);
    ff1_gemm<<<dim3(2, 1600), 256, 0, stream>>>(h1, W1, b1, ff1);
    ff2_ln2<<<3200, 256, 0, stream>>>(ff1, W2, b2, h1, ln2g, ln2b, outp);
}

// Round 7
// 660.031 us; speedup vs baseline: 1.6603x; 1.2141x over previous
//
#include <hip/hip_runtime.h>
#include <math.h>

// Problem constants
#define F_DIM 256
#define N_DIM 400
#define C_DIM 128
#define H_DIM 8
#define E_DIM 16
#define ROWS  (F_DIM * N_DIM)          // 102400
#define SBUF  (N_DIM * H_DIM * F_DIM * E_DIM)  // 13107200 floats per q/k/v buffer

typedef _Float16 half2_t __attribute__((ext_vector_type(2)));
typedef _Float16 f16x8   __attribute__((ext_vector_type(8)));
typedef float    f32x16  __attribute__((ext_vector_type(16)));
typedef float    f32x4   __attribute__((ext_vector_type(4)));

struct H2x4 { half2_t h[4]; };

// pack 8 consecutive fp32 (two float4) into an f16x8 fragment
__device__ inline f16x8 pack8(float4 a, float4 b) {
    H2x4 t;
    t.h[0] = __builtin_bit_cast(half2_t, __builtin_amdgcn_cvt_pkrtz(a.x, a.y));
    t.h[1] = __builtin_bit_cast(half2_t, __builtin_amdgcn_cvt_pkrtz(a.z, a.w));
    t.h[2] = __builtin_bit_cast(half2_t, __builtin_amdgcn_cvt_pkrtz(b.x, b.y));
    t.h[3] = __builtin_bit_cast(half2_t, __builtin_amdgcn_cvt_pkrtz(b.z, b.w));
    return __builtin_bit_cast(f16x8, t);
}

__device__ inline int iclamp256(int v) { return v < 0 ? 0 : (v > 256 ? 256 : v); }

// ---------------------------------------------------------------------------
// K0: tree_k / tree_v projections (unchanged)
// ---------------------------------------------------------------------------
__global__ __launch_bounds__(256) void tree_proj(
    const float* __restrict__ te, const float* __restrict__ Wtk,
    const float* __restrict__ Wtv, float* __restrict__ tk, float* __restrict__ tv)
{
    int n = blockIdx.x;
    int t = threadIdx.x;
    const float* W = (t < 128) ? Wtk : Wtv;
    float* outp    = (t < 128) ? tk : tv;
    int j = t & 127;
    float acc = 0.f;
    #pragma unroll 4
    for (int c = 0; c < 128; ++c)
        acc += te[n * 128 + c] * W[c * 128 + j];
    outp[n * 128 + j] = acc;
}

// ---------------------------------------------------------------------------
// K1: qkv GEMM via fp16 MFMA (unchanged)
// ---------------------------------------------------------------------------
__global__ __launch_bounds__(256) void qkv_gemm(
    const float* __restrict__ x, const float* __restrict__ Wq,
    const float* __restrict__ tk, const float* __restrict__ tv,
    float* __restrict__ qb, float* __restrict__ kb, float* __restrict__ vb)
{
    int tid  = threadIdx.x;
    int wave = tid >> 6, lane = tid & 63;
    int m32  = lane & 31, khalf = lane >> 5;
    int row0 = blockIdx.y * 64 + (wave & 1) * 32;
    int col0 = blockIdx.x * 64 + (wave >> 1) * 32;

    const float* xp = x  + (row0 + m32) * 128 + khalf * 8;
    const float* wp = Wq + (col0 + m32) * 128 + khalf * 8;

    f32x16 acc;
    #pragma unroll
    for (int i = 0; i < 16; ++i) acc[i] = 0.f;

    #pragma unroll
    for (int k0 = 0; k0 < 128; k0 += 16) {
        float4 xa = *(const float4*)(xp + k0);
        float4 xb = *(const float4*)(xp + k0 + 4);
        float4 wa = *(const float4*)(wp + k0);
        float4 wb = *(const float4*)(wp + k0 + 4);
        acc = __builtin_amdgcn_mfma_f32_32x32x16_f16(pack8(xa, xb), pack8(wa, wb), acc, 0, 0, 0);
    }

    int o   = col0 + m32;
    int sec = o >> 7;
    int rem = o & 127;
    int h = rem >> 4, e = rem & 15;
    #pragma unroll
    for (int reg = 0; reg < 16; ++reg) {
        int r = row0 + (reg & 3) + 8 * (reg >> 2) + 4 * khalf;  // r = f*400+n
        int f = r / 400;
        int n = r - f * 400;
        int dst = ((n * 8 + h) * 256 + f) * 16 + e;
        float val = acc[reg];
        if (sec == 0)       qb[dst] = val;
        else if (sec == 1)  kb[dst] = val + tk[n * 128 + rem];
        else                vb[dst] = val + tv[n * 128 + rem];
    }
}

// ---------------------------------------------------------------------------
// K2: MFMA flash attention per (n,h). 4 waves; wave w owns l in [64w,64w+64).
// S = QK^T (32x32x16 MFMA). bias1 = Q.emb[d] via window-GEMM + ds_bpermute.
// bias2 = K.emb[d] via shared R2 table (K_tile @ emb^T, MFMA, LDS gather).
// PV via 16x16x32 MFMA after wave-private LDS roundtrip of P.
// FIX r6->r7: denominator row-sum read only 16 of 32 P values (2 uint4).
// Now reads all 4 uint4 (32 halves). That bug made y ~2x (absmax 1.996).
// LDS ~62.3 KB. grid 3200, block 256.
// ---------------------------------------------------------------------------
#define KS_STRIDE 24    // halves per K/emb row (48B, b128-aligned, padded)
#define VT_STRIDE 264   // halves per V^T row
#define R2_STRIDE 296   // halves per R2 row (288 cols + pad)
#define PS_STRIDE 40    // halves per P row (80B, b128-aligned, odd-dword)

__global__ __launch_bounds__(256) void attn_kernel(
    const float* __restrict__ qb, const float* __restrict__ kb,
    const float* __restrict__ vb, const float* __restrict__ emb,
    float* __restrict__ y)
{
    __shared__ __align__(16) _Float16 Ksh[256 * KS_STRIDE];   // 12.3 KB
    __shared__ __align__(16) _Float16 Esh[257 * KS_STRIDE];   // 12.3 KB
    __shared__ __align__(16) _Float16 VshT[16 * VT_STRIDE];   // 8.4 KB
    __shared__ __align__(16) _Float16 R2sh[32 * R2_STRIDE];   // 18.9 KB
    __shared__ __align__(16) _Float16 Psh[4 * 32 * PS_STRIDE];// 10.2 KB

    int tid  = threadIdx.x;
    int wave = tid >> 6, lane = tid & 63;
    int bn   = blockIdx.x;            // n*8 + h
    int n    = bn >> 3, h = bn & 7;
    int base = bn * 4096;

    // ---- staging ----
    {
        int s = tid;
        const float4* kr = (const float4*)(kb + base + s * 16);
        float4 k0 = kr[0], k1 = kr[1], k2 = kr[2], k3 = kr[3];
        *(uint4*)(Ksh + s * KS_STRIDE)     = __builtin_bit_cast(uint4, pack8(k0, k1));
        *(uint4*)(Ksh + s * KS_STRIDE + 8) = __builtin_bit_cast(uint4, pack8(k2, k3));

        const float4* vr = (const float4*)(vb + base + s * 16);
        float4 v0 = vr[0], v1 = vr[1], v2 = vr[2], v3 = vr[3];
        float vv[16] = { v0.x,v0.y,v0.z,v0.w, v1.x,v1.y,v1.z,v1.w,
                         v2.x,v2.y,v2.z,v2.w, v3.x,v3.y,v3.z,v3.w };
        #pragma unroll
        for (int e = 0; e < 16; ++e)
            VshT[e * VT_STRIDE + s] = (_Float16)vv[e];
    }
    for (int rr = tid; rr < 257; rr += 256) {
        const float4* er = (const float4*)(emb + rr * 16);
        float4 e0 = er[0], e1 = er[1], e2 = er[2], e3 = er[3];
        *(uint4*)(Esh + rr * KS_STRIDE)     = __builtin_bit_cast(uint4, pack8(e0, e1));
        *(uint4*)(Esh + rr * KS_STRIDE + 8) = __builtin_bit_cast(uint4, pack8(e2, e3));
    }

    int nn  = lane & 31;            // score col / s-local / frag m-or-n index
    int kh  = lane >> 5;            // wave half (frag k split for 32-shapes)
    int khb = (lane & 32) << 2;     // bpermute addr offset into own half
    int cbase = 31 + 4 * kh - nn;   // window col base per lane
    int dbase = 4 * kh - nn;        // d offset per lane
    int q16 = (lane >> 4) & 3;      // quad for 16x16 shapes

    // Q fragments for this wave's two l-tiles (direct from global)
    f16x8 aq[2];
    #pragma unroll
    for (int lt = 0; lt < 2; ++lt) {
        const float* qp = qb + base + (64 * wave + 32 * lt + nn) * 16 + kh * 8;
        float4 qa = *(const float4*)qp;
        float4 qb4 = *(const float4*)(qp + 4);
        aq[lt] = pack8(qa, qb4);
    }

    f32x4 O[2][2];
    #pragma unroll
    for (int i = 0; i < 2; ++i)
        #pragma unroll
        for (int j = 0; j < 2; ++j)
            #pragma unroll
            for (int r = 0; r < 4; ++r) O[i][j][r] = 0.f;
    float denom = 0.f;

    _Float16* psw = Psh + wave * 32 * PS_STRIDE;

    __syncthreads();

    for (int st = 0; st < 8; ++st) {
        // K-tile fragment (A for R2, B for QK): row = 32*st + nn
        f16x8 bk = __builtin_bit_cast(f16x8,
            *(const uint4*)(Ksh + (32 * st + nn) * KS_STRIDE + kh * 8));

        // ---- shared R2 table: R2[s_local][d] = K[32st+s_local] . emb[d] ----
        for (int ct = wave; ct < 9; ct += 4) {
            int erow = 32 * ct + nn; if (erow > 256) erow = 256;
            f16x8 be = __builtin_bit_cast(f16x8,
                *(const uint4*)(Esh + erow * KS_STRIDE + kh * 8));
            f32x16 c2;
            #pragma unroll
            for (int i = 0; i < 16; ++i) c2[i] = 0.f;
            c2 = __builtin_amdgcn_mfma_f32_32x32x16_f16(bk, be, c2, 0, 0, 0);
            #pragma unroll
            for (int r = 0; r < 16; ++r) {
                int srow = (r & 3) + 8 * (r >> 2) + 4 * kh;
                R2sh[srow * R2_STRIDE + 32 * ct + nn] = (_Float16)c2[r];
            }
        }
        __syncthreads();   // R2 ready for all waves

        // PV B-fragment: V^T[e = lane&15][k = s-local = q16*8+j]
        f16x8 bv = __builtin_bit_cast(f16x8,
            *(const uint4*)(VshT + (lane & 15) * VT_STRIDE + 32 * st + q16 * 8));

        #pragma unroll
        for (int lt = 0; lt < 2; ++lt) {
            int U0 = 64 * wave + 32 * lt - 32 * st + 128;

            // scores
            f32x16 S;
            #pragma unroll
            for (int i = 0; i < 16; ++i) S[i] = 0.f;
            S = __builtin_amdgcn_mfma_f32_32x32x16_f16(aq[lt], bk, S, 0, 0, 0);

            // bias1 windows: W[m][c] = Q[l0+m] . emb[clamp(U0-31+c)]
            int br0 = iclamp256(U0 - 31 + nn);
            int br1 = iclamp256(U0 + 1 + nn);
            f16x8 be0 = __builtin_bit_cast(f16x8,
                *(const uint4*)(Esh + br0 * KS_STRIDE + kh * 8));
            f16x8 be1 = __builtin_bit_cast(f16x8,
                *(const uint4*)(Esh + br1 * KS_STRIDE + kh * 8));
            f32x16 W0, W1;
            #pragma unroll
            for (int i = 0; i < 16; ++i) { W0[i] = 0.f; W1[i] = 0.f; }
            W0 = __builtin_amdgcn_mfma_f32_32x32x16_f16(aq[lt], be0, W0, 0, 0, 0);
            W1 = __builtin_amdgcn_mfma_f32_32x32x16_f16(aq[lt], be1, W1, 0, 0, 0);

            #pragma unroll
            for (int r = 0; r < 16; ++r) {
                int rmr = (r & 3) + 8 * (r >> 2);
                int c   = rmr + cbase;                 // [0,62]
                int addr = ((c & 31) << 2) + khb;
                float b1a = __builtin_bit_cast(float,
                    __builtin_amdgcn_ds_bpermute(addr, __builtin_bit_cast(int, W0[r])));
                float b1b = __builtin_bit_cast(float,
                    __builtin_amdgcn_ds_bpermute(addr, __builtin_bit_cast(int, W1[r])));
                float b1 = (c < 32) ? b1a : b1b;
                int d = iclamp256(U0 + rmr + dbase);
                float b2 = (float)R2sh[nn * R2_STRIDE + d];
                float p = __expf((S[r] + b1 + b2) * 0.25f);
                int mloc = rmr + 4 * kh;
                psw[mloc * PS_STRIDE + nn] = (_Float16)p;
            }

            // denom: lane j (with j>>5==lt) sums its own row — ALL 32 values
            if ((lane >> 5) == lt) {
                const uint4* rp = (const uint4*)(psw + (lane & 31) * PS_STRIDE);
                uint4 u0 = rp[0], u1 = rp[1], u2 = rp[2], u3 = rp[3];
                half2_t hs0 =
                    (__builtin_bit_cast(half2_t, u0.x) + __builtin_bit_cast(half2_t, u0.y)) +
                    (__builtin_bit_cast(half2_t, u0.z) + __builtin_bit_cast(half2_t, u0.w));
                half2_t hs1 =
                    (__builtin_bit_cast(half2_t, u1.x) + __builtin_bit_cast(half2_t, u1.y)) +
                    (__builtin_bit_cast(half2_t, u1.z) + __builtin_bit_cast(half2_t, u1.w));
                half2_t hs2 =
                    (__builtin_bit_cast(half2_t, u2.x) + __builtin_bit_cast(half2_t, u2.y)) +
                    (__builtin_bit_cast(half2_t, u2.z) + __builtin_bit_cast(half2_t, u2.w));
                half2_t hs3 =
                    (__builtin_bit_cast(half2_t, u3.x) + __builtin_bit_cast(half2_t, u3.y)) +
                    (__builtin_bit_cast(half2_t, u3.z) + __builtin_bit_cast(half2_t, u3.w));
                half2_t hsum = (hs0 + hs1) + (hs2 + hs3);
                denom += (float)hsum.x + (float)hsum.y;
            }

            // PV: 2 sub-tiles of 16 l-rows each, K = 32 (this s-tile)
            #pragma unroll
            for (int a = 0; a < 2; ++a) {
                f16x8 ap = __builtin_bit_cast(f16x8,
                    *(const uint4*)(psw + (16 * a + (lane & 15)) * PS_STRIDE + q16 * 8));
                O[lt][a] = __builtin_amdgcn_mfma_f32_16x16x32_f16(ap, bv, O[lt][a], 0, 0, 0);
            }
        }
        __syncthreads();   // all reads of R2sh done before next st overwrites
    }

    // ---- epilogue: normalize + write ----
    float inv = 1.0f / denom;   // lane owns l = 64*wave + lane
    int iinv = __builtin_bit_cast(int, inv);
    #pragma unroll
    for (int lt = 0; lt < 2; ++lt) {
        #pragma unroll
        for (int a = 0; a < 2; ++a) {
            #pragma unroll
            for (int r = 0; r < 4; ++r) {
                int row  = q16 * 4 + r;
                int lloc = 32 * lt + 16 * a + row;
                float dv = __builtin_bit_cast(float,
                    __builtin_amdgcn_ds_bpermute(lloc << 2, iinv));
                int lg = 64 * wave + lloc;
                y[(lg * 400 + n) * 128 + h * 16 + (lane & 15)] = O[lt][a][r] * dv;
            }
        }
    }
}

// ---------------------------------------------------------------------------
// K3: gate+LN1 (unchanged)
// ---------------------------------------------------------------------------
__global__ __launch_bounds__(256) void gate_ln1(
    const float* __restrict__ x, const float* __restrict__ y,
    const float* __restrict__ Wb, const float* __restrict__ g,
    const float* __restrict__ b, float* __restrict__ h1)
{
    int tid  = threadIdx.x;
    int r    = blockIdx.x * 4 + (tid >> 6);
    int lane = tid & 63;
    int c    = lane * 2;

    float2 xv = *(const float2*)(x + r * 128 + c);
    float2 yv = *(const float2*)(y + r * 128 + c);
    float2 w0 = *(const float2*)(Wb + c);
    float2 w1 = *(const float2*)(Wb + 128 + c);
    float2 w2 = *(const float2*)(Wb + 256 + c);

    float sv = yv.x * w0.x + yv.y * w0.y
             + xv.x * w1.x + xv.y * w1.y
             + (yv.x - xv.x) * w2.x + (yv.y - xv.y) * w2.y;
    #pragma unroll
    for (int off = 32; off > 0; off >>= 1) sv += __shfl_xor(sv, off);
    float gate = 1.0f / (1.0f + __expf(-sv));

    float z0 = gate * xv.x + (1.0f - gate) * yv.x;
    float z1 = gate * xv.y + (1.0f - gate) * yv.y;
    float s1 = z0 + z1, s2 = z0 * z0 + z1 * z1;
    #pragma unroll
    for (int off = 32; off > 0; off >>= 1) {
        s1 += __shfl_xor(s1, off);
        s2 += __shfl_xor(s2, off);
    }
    float mu  = s1 * (1.0f / 128.0f);
    float var = s2 * (1.0f / 128.0f) - mu * mu;
    float rs  = rsqrtf(var + 1e-5f);

    float2 gv = *(const float2*)(g + c);
    float2 bv = *(const float2*)(b + c);
    float2 ov;
    ov.x = (z0 - mu) * rs * gv.x + bv.x;
    ov.y = (z1 - mu) * rs * gv.y + bv.y;
    *(float2*)(h1 + r * 128 + c) = ov;
}

// ---------------------------------------------------------------------------
// K4: ff1 fp16 MFMA + exact GELU (unchanged)
// ---------------------------------------------------------------------------
__global__ __launch_bounds__(256) void ff1_gemm(
    const float* __restrict__ A, const float* __restrict__ W,
    const float* __restrict__ bias, float* __restrict__ outp)
{
    int tid  = threadIdx.x;
    int wave = tid >> 6, lane = tid & 63;
    int m32  = lane & 31, khalf = lane >> 5;
    int row0 = blockIdx.y * 64 + (wave & 1) * 32;
    int col0 = blockIdx.x * 64 + (wave >> 1) * 32;

    const float* ap = A + (row0 + m32) * 128 + khalf * 8;
    const float* wp = W + (col0 + m32) * 128 + khalf * 8;

    f32x16 acc;
    #pragma unroll
    for (int i = 0; i < 16; ++i) acc[i] = 0.f;

    #pragma unroll
    for (int k0 = 0; k0 < 128; k0 += 16) {
        float4 aa = *(const float4*)(ap + k0);
        float4 ab = *(const float4*)(ap + k0 + 4);
        float4 wa = *(const float4*)(wp + k0);
        float4 wb = *(const float4*)(wp + k0 + 4);
        acc = __builtin_amdgcn_mfma_f32_32x32x16_f16(pack8(aa, ab), pack8(wa, wb), acc, 0, 0, 0);
    }

    int   c  = col0 + m32;
    float bi = bias[c];
    #pragma unroll
    for (int reg = 0; reg < 16; ++reg) {
        int r = row0 + (reg & 3) + 8 * (reg >> 2) + 4 * khalf;
        float v = acc[reg] + bi;
        v = 0.5f * v * (1.0f + erff(v * 0.70710678118654752f));  // exact GELU
        outp[r * 128 + c] = v;
    }
}

// ---------------------------------------------------------------------------
// K5: ff2 + LN2 fp16 MFMA (unchanged)
// ---------------------------------------------------------------------------
__global__ __launch_bounds__(256) void ff2_ln2(
    const float* __restrict__ A, const float* __restrict__ W2,
    const float* __restrict__ b2, const float* __restrict__ h1,
    const float* __restrict__ g, const float* __restrict__ bb,
    float* __restrict__ outp)
{
    __shared__ float Cs[32 * 132];
    int tid  = threadIdx.x;
    int wave = tid >> 6, lane = tid & 63;
    int m32  = lane & 31, khalf = lane >> 5;
    int row0 = blockIdx.x * 32;
    int col0 = wave * 32;

    const float* ap = A  + (row0 + m32) * 128 + khalf * 8;
    const float* wp = W2 + (col0 + m32) * 128 + khalf * 8;

    f32x16 acc;
    #pragma unroll
    for (int i = 0; i < 16; ++i) acc[i] = 0.f;

    #pragma unroll
    for (int k0 = 0; k0 < 128; k0 += 16) {
        float4 aa = *(const float4*)(ap + k0);
        float4 ab = *(const float4*)(ap + k0 + 4);
        float4 wa = *(const float4*)(wp + k0);
        float4 wb = *(const float4*)(wp + k0 + 4);
        acc = __builtin_amdgcn_mfma_f32_32x32x16_f16(pack8(aa, ab), pack8(wa, wb), acc, 0, 0, 0);
    }

    #pragma unroll
    for (int reg = 0; reg < 16; ++reg) {
        int rloc = (reg & 3) + 8 * (reg >> 2) + 4 * khalf;
        Cs[rloc * 132 + col0 + m32] = acc[reg];
    }
    __syncthreads();

    int rloc = tid >> 3, seg = (tid & 7) * 16;
    int r = row0 + rloc;
    float z[16];
    float s1 = 0.f, s2 = 0.f;
    #pragma unroll
    for (int j4 = 0; j4 < 4; ++j4) {
        float4 cv = *(const float4*)(Cs + rloc * 132 + seg + j4 * 4);
        float4 hv = *(const float4*)(h1 + r * 128 + seg + j4 * 4);
        float4 bv = *(const float4*)(b2 + seg + j4 * 4);
        z[j4*4+0] = cv.x + bv.x + hv.x;
        z[j4*4+1] = cv.y + bv.y + hv.y;
        z[j4*4+2] = cv.z + bv.z + hv.z;
        z[j4*4+3] = cv.w + bv.w + hv.w;
        s1 += z[j4*4+0] + z[j4*4+1] + z[j4*4+2] + z[j4*4+3];
        s2 += z[j4*4+0]*z[j4*4+0] + z[j4*4+1]*z[j4*4+1]
            + z[j4*4+2]*z[j4*4+2] + z[j4*4+3]*z[j4*4+3];
    }
    #pragma unroll
    for (int off = 4; off > 0; off >>= 1) {
        s1 += __shfl_xor(s1, off);
        s2 += __shfl_xor(s2, off);
    }
    float mu  = s1 * (1.0f / 128.0f);
    float var = s2 * (1.0f / 128.0f) - mu * mu;
    float rs  = rsqrtf(var + 1e-5f);
    #pragma unroll
    for (int j4 = 0; j4 < 4; ++j4) {
        float4 gv = *(const float4*)(g  + seg + j4 * 4);
        float4 bv = *(const float4*)(bb + seg + j4 * 4);
        float4 ov;
        ov.x = (z[j4*4+0] - mu) * rs * gv.x + bv.x;
        ov.y = (z[j4*4+1] - mu) * rs * gv.y + bv.y;
        ov.z = (z[j4*4+2] - mu) * rs * gv.z + bv.z;
        ov.w = (z[j4*4+3] - mu) * rs * gv.w + bv.w;
        *(float4*)(outp + r * 128 + seg + j4 * 4) = ov;
    }
}

// ---------------------------------------------------------------------------
extern "C" void kernel_launch(void* const* d_in, const int* in_sizes, int n_in,
                              void* d_out, int out_size, void* d_ws, size_t ws_size,
                              hipStream_t stream)
{
    const float* x     = (const float*)d_in[0];
    const float* te    = (const float*)d_in[1];
    const float* Wqkv  = (const float*)d_in[2];
    const float* Wtk   = (const float*)d_in[3];
    const float* Wtv   = (const float*)d_in[4];
    const float* emb   = (const float*)d_in[5];
    const float* Wbeta = (const float*)d_in[6];
    const float* ln1g  = (const float*)d_in[7];
    const float* ln1b  = (const float*)d_in[8];
    const float* ln2g  = (const float*)d_in[9];
    const float* ln2b  = (const float*)d_in[10];
    const float* W1    = (const float*)d_in[11];
    const float* b1    = (const float*)d_in[12];
    const float* W2    = (const float*)d_in[13];
    const float* b2    = (const float*)d_in[14];
    float* outp = (float*)d_out;

    float* ws = (float*)d_ws;
    float* tk = ws;                       // 51200
    float* tv = ws + 51200;               // 51200
    float* qb = ws + 102400;              // SBUF
    float* kb = qb + SBUF;                // SBUF
    float* vb = kb + SBUF;                // SBUF
    float* yb = vb + SBUF;                // SBUF  (f,n,c)
    float* h1 = kb;                       // reuse: k dead after attention
    float* ff1 = qb;                      // reuse: q dead after attention

    tree_proj<<<400, 256, 0, stream>>>(te, Wtk, Wtv, tk, tv);
    qkv_gemm<<<dim3(6, 1600), 256, 0, stream>>>(x, Wqkv, tk, tv, qb, kb, vb);
    attn_kernel<<<3200, 256, 0, stream>>>(qb, kb, vb, emb, yb);
    gate_ln1<<<ROWS / 4, 256, 0, stream>>>(x, yb, Wbeta, ln1g, ln1b, h1);
    ff1_gemm<<<dim3(2, 1600), 256, 0, stream>>>(h1, W1, b1, ff1);
    ff2_ln2<<<3200, 256, 0, stream>>>(ff1, W2, b2, h1, ln2g, ln2b, outp);
}